// Round 1
// baseline (192.562 us; speedup 1.0000x reference)
//
#include <hip/hip_runtime.h>

typedef unsigned short u16;
typedef unsigned int u32;
typedef unsigned char u8;

typedef _Float16 f16x8 __attribute__((ext_vector_type(8)));   // 8 f16 (4 VGPRs)
typedef _Float16 f16x2 __attribute__((ext_vector_type(2)));   // packed pair
typedef __attribute__((ext_vector_type(4))) float f32x4;

// B=4, NA=NB=2048, IN=128, H=8, DH=16, C=128, OUT=128
// 3-launch pipeline: kprep (mask-pack + proj-B + e-tables + WtO transpose, fused),
// kattn (f16 MFMA flash with LDS-staged EB/GB AND LDS-staged mask tile), kout.

#if __has_builtin(__builtin_amdgcn_sbfe)
#define SEXTBIT(m, j) ((u32)__builtin_amdgcn_sbfe((int)(m), (u32)(j), 1u))
#else
#define SEXTBIT(m, j) ((u32)(((int)((m) << (31 - (j)))) >> 31))
#endif

__global__ __launch_bounds__(256) void kzero(float* __restrict__ out){
  out[blockIdx.x * 256 + threadIdx.x] = 0.f;
}

// ---------------- fused prep ----------------
// blocks [0,256): proj-B -> fragment-major f16 zF   (inlines WfB gather from WBw)
// blocks [256,768): e-tables (inlines vA/vB/cA/cB fold)
// blocks [768,832): WtO transpose of Ww
// blocks [832,2880): mask -> packed bits (encoding self-detected)
__global__ __launch_bounds__(256) void kprep(
    const void* __restrict__ maskv, u32* __restrict__ Mb,
    const float* __restrict__ hA, const float* __restrict__ hB,
    const float* __restrict__ WAw, const float* __restrict__ WAb,
    const float* __restrict__ aAw, const float* __restrict__ aAb,
    const float* __restrict__ WBw, const float* __restrict__ WBb,
    const float* __restrict__ aBw, const float* __restrict__ aBb,
    const float* __restrict__ Ww, float* __restrict__ WtO,
    uint4* __restrict__ zF,
    float* __restrict__ EAe, float* __restrict__ EA01e,
    u32* __restrict__ EBh, u32* __restrict__ GBh){
  __shared__ float smem[12416];       // 49,664 B; branch-local overlays
  int gid = blockIdx.x, t = threadIdx.x;

  if (gid < 256){
    // ---------------- proj-B ----------------
    float* h_l = smem;                // 32*132 = 4224
    float* W_l = smem + 4224;         // 64*128 = 8192
    float* T   = smem + 4224;         // 128*33 = 4224, overlays W_l after compute
    int R0 = gid * 32;

    for (int j = 0; j < 4; ++j){
      int idx4 = t + 256 * j;
      int r = idx4 >> 5, k0 = (idx4 & 31) * 4;
      *(float4*)&h_l[r * 132 + k0] = *(const float4*)&hB[(size_t)(R0 + r) * 128 + k0];
    }

    int cg = t & 15, rg = t >> 4;
    float acc[2][8];
    for (int i = 0; i < 2; ++i) for (int s = 0; s < 8; ++s) acc[i][s] = 0.f;

    for (int kc = 0; kc < 2; ++kc){
      __syncthreads();
      for (int j = 0; j < 8; ++j){
        int idx4 = t + 256 * j;
        int k = idx4 >> 5, c0 = (idx4 & 31) * 4;
        // WfB[(kc*64+k)*128 + c] == WBw[(c>>4)*2048 + (kc*64+k)*16 + (c&15)], contiguous x4
        *(float4*)&W_l[k * 128 + c0] =
          *(const float4*)&WBw[(size_t)(c0 >> 4) * 2048 + (kc * 64 + k) * 16 + (c0 & 15)];
      }
      __syncthreads();
      for (int k = 0; k < 64; ++k){
        int kk = kc * 64 + k;
        float4 w0 = *(const float4*)&W_l[k * 128 + cg * 8];
        float4 w1 = *(const float4*)&W_l[k * 128 + cg * 8 + 4];
        float wv[8] = {w0.x, w0.y, w0.z, w0.w, w1.x, w1.y, w1.z, w1.w};
        #pragma unroll
        for (int i = 0; i < 2; ++i){
          float hv = h_l[(rg * 2 + i) * 132 + kk];
          #pragma unroll
          for (int s = 0; s < 8; ++s) acc[i][s] = fmaf(hv, wv[s], acc[i][s]);
        }
      }
    }
    __syncthreads();                  // W_l reads done before T overlay
    for (int i = 0; i < 2; ++i)
      #pragma unroll
      for (int s = 0; s < 8; ++s)
        T[(cg * 8 + s) * 33 + rg * 2 + i] = acc[i][s] + WBb[cg * 8 + s];
    __syncthreads();

    int b = R0 >> 11;
    int mblk = (R0 & 2047) >> 5;
    for (int it = t; it < 512; it += 256){
      int h = it >> 6, lane = it & 63;
      int d = lane & 15, mq = (lane >> 4) * 8;
      const float* Tp = &T[(h * 16 + d) * 33 + mq];
      u32 wv2[4];
      #pragma unroll
      for (int p = 0; p < 4; ++p){
        union { f16x2 h2; u32 u; } c;
        c.h2 = (f16x2){(_Float16)Tp[p * 2], (_Float16)Tp[p * 2 + 1]};
        wv2[p] = c.u;
      }
      zF[((size_t)((b * 8 + h) * 64) + mblk) * 64 + lane] = make_uint4(wv2[0], wv2[1], wv2[2], wv2[3]);
    }
  } else if (gid < 768){
    // ---------------- e-tables (fold inlined) ----------------
    float* h_l = smem;                // 32*132
    float* v_l = smem + 4224;         // 8*132
    float* c_l = smem + 5280;         // 8
    float* a_l = smem + 5288;         // 128
    int ge = gid - 256;
    int X = ge >> 8;
    int r0 = (ge & 255) * 32;
    const float* hp  = X ? hB  : hA;
    const float* Wp  = X ? WBw : WAw;
    const float* Wbp = X ? WBb : WAb;
    const float* awp = X ? aBw : aAw;
    const float* abp = X ? aBb : aAb;

    for (int j = 0; j < 4; ++j){
      int idx4 = t + 256 * j;
      int r = idx4 >> 5, k0 = (idx4 & 31) * 4;
      *(float4*)&h_l[r * 132 + k0] = *(const float4*)&hp[(size_t)(r0 + r) * 128 + k0];
    }
    if (t < 128) a_l[t] = awp[t];
    __syncthreads();
    #pragma unroll
    for (int p = 0; p < 4; ++p){
      int idx = t + 256 * p;
      int h = idx >> 7, i = idx & 127;
      const float* wrow = Wp + (size_t)h * 2048 + i * 16;
      float s = 0.f;
      #pragma unroll
      for (int d = 0; d < 16; ++d) s = fmaf(wrow[d], a_l[h * 16 + d], s);
      v_l[h * 132 + i] = s;
    }
    if (t < 8){
      float s = abp[t];
      #pragma unroll
      for (int d = 0; d < 16; ++d) s = fmaf(Wbp[t * 16 + d], a_l[t * 16 + d], s);
      c_l[t] = s;
    }
    __syncthreads();

    int r = t >> 3, h = t & 7;
    float acc = c_l[h];
    #pragma unroll
    for (int k0 = 0; k0 < 128; k0 += 4){
      float4 hv = *(const float4*)&h_l[r * 132 + k0];
      float4 vv = *(const float4*)&v_l[h * 132 + k0];
      acc = fmaf(hv.x, vv.x, acc); acc = fmaf(hv.y, vv.y, acc);
      acc = fmaf(hv.z, vv.z, acc); acc = fmaf(hv.w, vv.w, acc);
    }
    int row = r0 + r;
    int b = row >> 11, n = row & 2047;
    float e0 = __expf(acc), e1 = __expf(0.01f * acc);
    if (X){
      float p0 = __shfl_xor(e0, 8, 64);
      float p1 = __shfl_xor(e1, 8, 64);
      if ((((t & 63) >> 3) & 1) == 0){
        union { f16x2 h2; u32 u; } c0, c1;
        c0.h2 = (f16x2){(_Float16)e0, (_Float16)p0};
        c1.h2 = (f16x2){(_Float16)e1, (_Float16)p1};
        u32 di = (u32)((b * 8 + h) * 1024 + (n >> 1));
        EBh[di] = c0.u;
        GBh[di] = c1.u;
      }
    } else {
      size_t idx = (size_t)(b * 8 + h) * 2048 + n;
      EAe[idx] = e0; EA01e[idx] = e1;
    }
  } else if (gid < 832){
    // ---------------- WtO transpose ----------------
    int j = gid - 768;
    int idx = j * 256 + t;
    int c = idx >> 7, o = idx & 127;
    WtO[idx] = Ww[o * 128 + c];
  } else {
    // ---------------- mask -> packed bits ----------------
    int mg = gid - 832;
    int* flg = (int*)smem;            // [aw, ab, ah]
    if (t == 0){ flg[0] = 1; flg[1] = 1; flg[2] = 1; }
    __syncthreads();
    {
      const u32* mw = (const u32*)maskv;   // same first 1024 words in every block
      int aw = 1, ah = 1, ab = 1;
      #pragma unroll
      for (int jj = 0; jj < 4; ++jj){
        u32 m = mw[t + 256 * jj];
        if (!(m == 0u || m == 1u || m == 0x3F800000u)) aw = 0;
        u32 lo = m & 0xFFFFu, hi = m >> 16;
        if (!((lo == 0u || lo == 1u || lo == 0x3F80u) && (hi == 0u || hi == 1u || hi == 0x3F80u))) ah = 0;
        if (m & ~0x01010101u) ab = 0;
      }
      if (!aw) atomicAnd(&flg[0], 0);
      if (!ah) atomicAnd(&flg[2], 0);
      if (!ab) atomicAnd(&flg[1], 0);
    }
    __syncthreads();
    int Fm = 0;
    if (flg[0]) Fm = 0; else if (flg[1]) Fm = 1; else if (flg[2]) Fm = 2;

    if (Fm == 0){
      int lane = t & 63;
      int wid = mg * 4 + (t >> 6);       // 8192 waves
      const u32* mw = (const u32*)maskv;
      size_t base = (size_t)wid * 2048;  // 32 iters x 64 words
      #pragma unroll 4
      for (int i = 0; i < 32; ++i){
        u32 v = mw[base + i * 64 + lane];
        unsigned long long bal = __ballot(v != 0u);
        if (lane < 2) Mb[(base + i * 64) / 32 + lane] = (u32)(bal >> (32 * lane));
      }
      return;
    }
    int oid = mg * 256 + t;              // one packed word per thread
    u32 bits = 0;
    if (Fm == 1){
      const uint4* mp = (const uint4*)maskv + (size_t)oid * 2;
      #pragma unroll
      for (int k = 0; k < 2; ++k){
        uint4 v = mp[k];
        u32 w[4] = {v.x, v.y, v.z, v.w};
        #pragma unroll
        for (int q = 0; q < 4; ++q)
          #pragma unroll
          for (int bb = 0; bb < 4; ++bb)
            bits |= ((w[q] >> (8*bb)) & 255u ? 1u : 0u) << (k*16 + q*4 + bb);
      }
    } else {
      const uint4* mp = (const uint4*)maskv + (size_t)oid * 4;
      #pragma unroll
      for (int k = 0; k < 4; ++k){
        uint4 v = mp[k];
        u32 w[4] = {v.x, v.y, v.z, v.w};
        #pragma unroll
        for (int q = 0; q < 4; ++q){
          bits |= ((w[q] & 0xFFFFu) ? 1u : 0u) << (k*8 + q*2);
          bits |= ((w[q] >> 16)     ? 1u : 0u) << (k*8 + q*2 + 1);
        }
      }
    }
    Mb[oid] = bits;
  }
}

// ---------------- attention: f16 MFMA flash, LDS-staged EB/GB + mask, m-split x4 ----------------
__global__ __launch_bounds__(256) void kattn(const uint4* __restrict__ zF,
                                             const float* __restrict__ EAe, const float* __restrict__ EA01e,
                                             const u32* __restrict__ EBh, const u32* __restrict__ GBh,
                                             const u32* __restrict__ Mb,
                                             float* __restrict__ cat){
  __shared__ u32 EB_l[1024];         // full head: 2048 m as 1024 f16-pairs
  __shared__ u32 GB_l[1024];
  __shared__ u32 Mb_l[32 * 65];      // 32 n-rows x 64 m-words, stride-65 pad (conflict-free)
  __shared__ float red[3][32][17];   // [source wave-1][local row][16 cols + L]
  int t = threadIdx.x;
  int w = t >> 6, lane = t & 63;     // w = m-quarter
  int gid = blockIdx.x;              // 2048
  int h  = gid & 7;
  int nt = (gid >> 3) & 63;
  int b  = gid >> 9;
  int n0 = nt * 32;
  int nl = lane & 15, q = lane >> 4, qs = q * 8;

  // stage EB/GB (4KB+4KB) and the 8KB mask tile, all coalesced
  {
    const uint4* src0 = (const uint4*)(EBh + (size_t)(b * 8 + h) * 1024);
    const uint4* src1 = (const uint4*)(GBh + (size_t)(b * 8 + h) * 1024);
    ((uint4*)EB_l)[t] = src0[t];
    ((uint4*)GB_l)[t] = src1[t];
    const uint4* ms = (const uint4*)(Mb + ((size_t)b * 2048 + n0) * 64);
    uint4 m0v = ms[t * 2], m1v = ms[t * 2 + 1];
    int rr = t >> 3, cc = (t & 7) * 8;
    u32* dst = Mb_l + rr * 65 + cc;  // write banks 2-way max (free)
    dst[0] = m0v.x; dst[1] = m0v.y; dst[2] = m0v.z; dst[3] = m0v.w;
    dst[4] = m1v.x; dst[5] = m1v.y; dst[6] = m1v.z; dst[7] = m1v.w;
  }

  size_t ebase = (size_t)(b * 8 + h) * 2048;
  _Float16 ea0h  = (_Float16)EAe  [ebase + n0 + nl];
  _Float16 ea0sh = (_Float16)EA01e[ebase + n0 + nl];
  _Float16 ea1h  = (_Float16)EAe  [ebase + n0 + 16 + nl];
  _Float16 ea1sh = (_Float16)EA01e[ebase + n0 + 16 + nl];
  f16x2 ea0_2  = (f16x2){ea0h,  ea0h};
  f16x2 ea0s_2 = (f16x2){ea0sh, ea0sh};
  f16x2 ea1_2  = (f16x2){ea1h,  ea1h};
  f16x2 ea1s_2 = (f16x2){ea1sh, ea1sh};

  const u32* EBq = EB_l + w * 256;    // this wave's quarter (LDS)
  const u32* GBq = GB_l + w * 256;
  const u32* Mrow0 = Mb_l + nl * 65 + w * 16;        // row n0+nl
  const u32* Mrow1 = Mb_l + (nl + 16) * 65 + w * 16; // row n0+16+nl
  const uint4* zFp = zF + ((size_t)(b * 8 + h) * 64 + w * 16) * 64 + lane;  // coalesced

  f32x4 acc0 = {0.f,0.f,0.f,0.f}, acc1 = {0.f,0.f,0.f,0.f};
  f32x4 lcc0 = {0.f,0.f,0.f,0.f}, lcc1 = {0.f,0.f,0.f,0.f};
  union { u32 u[4]; f16x8 v; } onesu;
  onesu.u[0] = 0x3C003C00u; onesu.u[1] = 0x3C003C00u;
  onesu.u[2] = 0x3C003C00u; onesu.u[3] = 0x3C003C00u;
  const f16x8 ones = onesu.v;

  __syncthreads();                    // staging complete

  uint4 Azu, Bzu;
  #define LOADA(sp) do{ Azu = zFp[(size_t)(sp) * 64]; }while(0)
  #define LOADB(sp) do{ Bzu = zFp[(size_t)(sp) * 64]; }while(0)
  #define COMP(sp,ZU_) do{ \
    uint4 EB_ = *(const uint4*)(EBq + (sp) * 16 + q * 4); \
    uint4 GB_ = *(const uint4*)(GBq + (sp) * 16 + q * 4); \
    u32 mb0 = Mrow0[sp] >> qs; \
    u32 mb1 = Mrow1[sp] >> qs; \
    u32 ebu[4] = {EB_.x, EB_.y, EB_.z, EB_.w}; \
    u32 gbu[4] = {GB_.x, GB_.y, GB_.z, GB_.w}; \
    union { u32 u[4]; f16x8 v; } a0, a1; \
    _Pragma("unroll") \
    for (int p = 0; p < 4; ++p){ \
      int j0 = 2*p, j1 = 2*p + 1; \
      u32 k00 = SEXTBIT(mb0, j0); \
      u32 k01 = SEXTBIT(mb0, j1); \
      u32 k10 = SEXTBIT(mb1, j0); \
      u32 k11 = SEXTBIT(mb1, j1); \
      u32 kc0 = __builtin_amdgcn_perm(k01, k00, 0x05040100u); \
      u32 kc1 = __builtin_amdgcn_perm(k11, k10, 0x05040100u); \
      union { u32 u; f16x2 h2; } eb, gb, r0u, r1u; \
      eb.u = ebu[p]; gb.u = gbu[p]; \
      r0u.h2 = __builtin_elementwise_max(ea0_2 * eb.h2, ea0s_2 * gb.h2); \
      r1u.h2 = __builtin_elementwise_max(ea1_2 * eb.h2, ea1s_2 * gb.h2); \
      a0.u[p] = r0u.u & kc0; \
      a1.u[p] = r1u.u & kc1; \
    } \
    union { uint4 u; f16x8 v; } zu; zu.u = ZU_; \
    acc0 = __builtin_amdgcn_mfma_f32_16x16x32_f16(a0.v, zu.v, acc0, 0, 0, 0); \
    lcc0 = __builtin_amdgcn_mfma_f32_16x16x32_f16(a0.v, ones, lcc0, 0, 0, 0); \
    acc1 = __builtin_amdgcn_mfma_f32_16x16x32_f16(a1.v, zu.v, acc1, 0, 0, 0); \
    lcc1 = __builtin_amdgcn_mfma_f32_16x16x32_f16(a1.v, ones, lcc1, 0, 0, 0); }while(0)

  LOADA(0);
  LOADB(1);
  #pragma unroll 4
  for (int s = 0; s < 16; s += 2){
    COMP(s, Azu);
    LOADA(s + 2);                        // <=2-step overrun stays inside ws
    COMP(s + 1, Bzu);
    LOADB(s + 3);
  }
  #undef LOADA
  #undef LOADB
  #undef COMP

  if (w > 0){
    #pragma unroll
    for (int r = 0; r < 4; ++r){
      int row = q * 4 + r;
      red[w - 1][row][nl]      = acc0[r];
      red[w - 1][row + 16][nl] = acc1[r];
    }
    if (nl == 0){
      #pragma unroll
      for (int r = 0; r < 4; ++r){
        red[w - 1][q * 4 + r][16]      = lcc0[r];
        red[w - 1][q * 4 + r + 16][16] = lcc1[r];
      }
    }
  }
  __syncthreads();
  if (w == 0){
    #pragma unroll
    for (int r = 0; r < 4; ++r){
      int row = q * 4 + r;
      float a0 = acc0[r] + red[0][row][nl]      + red[1][row][nl]      + red[2][row][nl];
      float a1 = acc1[r] + red[0][row + 16][nl] + red[1][row + 16][nl] + red[2][row + 16][nl];
      float L0 = lcc0[r] + red[0][row][16]      + red[1][row][16]      + red[2][row][16];
      float L1 = lcc1[r] + red[0][row + 16][16] + red[1][row + 16][16] + red[2][row + 16][16];
      float r0 = (L0 > 0.f) ? 1.f / L0 : 0.f;
      float r1 = (L1 > 0.f) ? 1.f / L1 : 0.f;
      cat[((size_t)(b * 2048) + n0 + row)      * 128 + h * 16 + nl] = a0 * r0;
      cat[((size_t)(b * 2048) + n0 + 16 + row) * 128 + h * 16 + nl] = a1 * r1;
    }
  }
}

// ---------------- output GEMM: out = cat @ WtO + Wb ----------------
__global__ __launch_bounds__(256) void kout(const float* __restrict__ cat,
                                            const float* __restrict__ WtO, const float* __restrict__ Wb,
                                            float* __restrict__ out){
  __shared__ float cat_l[32 * 132];
  __shared__ float Wt_l[64 * 128];
  int R0 = blockIdx.x * 32;
  int t = threadIdx.x;

  for (int jj = 0; jj < 4; ++jj){
    int idx4 = t + 256 * jj;
    int r = idx4 >> 5, c0 = (idx4 & 31) * 4;
    *(float4*)&cat_l[r * 132 + c0] = *(const float4*)&cat[((size_t)R0 + r) * 128 + c0];
  }

  int og = t & 15, rg = t >> 4;
  float acc[2][8];
  for (int i = 0; i < 2; ++i) for (int s = 0; s < 8; ++s) acc[i][s] = 0.f;

  for (int kc = 0; kc < 2; ++kc){
    __syncthreads();
    for (int j = 0; j < 8; ++j){
      int idx4 = t + 256 * j;
      int k = idx4 >> 5, o0 = (idx4 & 31) * 4;
      *(float4*)&Wt_l[k * 128 + o0] = *(const float4*)&WtO[(kc * 64 + k) * 128 + o0];
    }
    __syncthreads();
    for (int k = 0; k < 64; ++k){
      int kk = kc * 64 + k;
      float4 w0 = *(const float4*)&Wt_l[k * 128 + og * 8];
      float4 w1 = *(const float4*)&Wt_l[k * 128 + og * 8 + 4];
      float wv[8] = {w0.x, w0.y, w0.z, w0.w, w1.x, w1.y, w1.z, w1.w};
      #pragma unroll
      for (int i = 0; i < 2; ++i){
        float cv = cat_l[(rg * 2 + i) * 132 + kk];
        #pragma unroll
        for (int s = 0; s < 8; ++s) acc[i][s] = fmaf(cv, wv[s], acc[i][s]);
      }
    }
  }

  for (int i = 0; i < 2; ++i){
    int r = rg * 2 + i;
    float* op = out + (size_t)(R0 + r) * 128 + og * 8;
    *(float4*)(op)     = make_float4(acc[i][0]+Wb[og*8+0], acc[i][1]+Wb[og*8+1], acc[i][2]+Wb[og*8+2], acc[i][3]+Wb[og*8+3]);
    *(float4*)(op + 4) = make_float4(acc[i][4]+Wb[og*8+4], acc[i][5]+Wb[og*8+5], acc[i][6]+Wb[og*8+6], acc[i][7]+Wb[og*8+7]);
  }
}

extern "C" void kernel_launch(void* const* d_in, const int* in_sizes, int n_in,
                              void* d_out, int out_size, void* d_ws, size_t ws_size,
                              hipStream_t stream) {
  const float* hA  = (const float*)d_in[0];
  const float* hB  = (const float*)d_in[1];
  const void* maskv= d_in[2];
  const float* WAw = (const float*)d_in[3];
  const float* WAb = (const float*)d_in[4];
  const float* WBw = (const float*)d_in[5];
  const float* WBb = (const float*)d_in[6];
  const float* aAw = (const float*)d_in[7];
  const float* aAb = (const float*)d_in[8];
  const float* aBw = (const float*)d_in[9];
  const float* aBb = (const float*)d_in[10];
  const float* Ww  = (const float*)d_in[11];
  const float* Wb  = (const float*)d_in[12];

  float* ws   = (float*)d_ws;
  uint4* zF   = (uint4*)ws;           // 131,072 uint4 = 524,288 float slots
  float* EAe  = ws + 524288;          // 65,536
  float* EA01e= ws + 589824;          // 65,536
  u32*  EBh   = (u32*)(ws + 655360);  // 32,768 dwords used (slot 65,536)
  u32*  GBh   = (u32*)(ws + 720896);  // 32,768 dwords used (slot 65,536)
  // ws + 786432: 16,384 (unused, former WfB)
  float* WtO  = ws + 802816;          // 16,384
  // ws + 819200 .. 821272: former vA/vB/cA/cB (unused)
  u32*  Mb    = (u32*)(ws + 821272);  // 524,288
  float* cat  = ws + 1345560;         // 1,048,576 -> total 2,394,136 floats

  if (ws_size < 2394136ull * 4ull){
    kzero<<<4096, 256, 0, stream>>>((float*)d_out);
    return;
  }

  kprep<<<2880, 256, 0, stream>>>(maskv, Mb, hA, hB,
                                  WAw, WAb, aAw, aAb,
                                  WBw, WBb, aBw, aBb,
                                  Ww, WtO, zF, EAe, EA01e, EBh, GBh);
  kattn<<<2048, 256, 0, stream>>>(zF, EAe, EA01e, EBh, GBh, Mb, cat);
  kout <<<256, 256, 0, stream>>>(cat, WtO, Wb, (float*)d_out);
}

// Round 2
// 175.905 us; speedup vs baseline: 1.0947x; 1.0947x over previous
//
#include <hip/hip_runtime.h>

typedef unsigned short u16;
typedef unsigned int u32;
typedef unsigned char u8;

typedef _Float16 f16x8 __attribute__((ext_vector_type(8)));   // 8 f16 (4 VGPRs)
typedef _Float16 f16x2 __attribute__((ext_vector_type(2)));   // packed pair
typedef __attribute__((ext_vector_type(4))) float f32x4;

// B=4, NA=NB=2048, IN=128, H=8, DH=16, C=128, OUT=128
// 4-launch pipeline:
//   kmask  (mask -> packed bits, tiny LDS -> full occupancy)
//   kprep  (proj-B + e-tables + WtO transpose, fused; 49.6KB LDS is fine here)
//   kattn  (f16 MFMA flash, LDS-staged EB/GB + mask tile)
//   kout   (output GEMM)

#if __has_builtin(__builtin_amdgcn_sbfe)
#define SEXTBIT(m, j) ((u32)__builtin_amdgcn_sbfe((int)(m), (u32)(j), 1u))
#else
#define SEXTBIT(m, j) ((u32)(((int)((m) << (31 - (j)))) >> 31))
#endif

__global__ __launch_bounds__(256) void kzero(float* __restrict__ out){
  out[blockIdx.x * 256 + threadIdx.x] = 0.f;
}

// ---------------- mask -> packed bits, encoding self-detected ----------------
__global__ __launch_bounds__(256) void kmask(const void* __restrict__ maskv,
                                             u32* __restrict__ Mb){
  __shared__ int s_aw, s_ab, s_ah;
  int t = threadIdx.x;
  if (t == 0){ s_aw = 1; s_ab = 1; s_ah = 1; }
  __syncthreads();
  {
    const u32* mw = (const u32*)maskv;   // same first 1024 words in every block
    int aw = 1, ah = 1, ab = 1;
    #pragma unroll
    for (int j = 0; j < 4; ++j){
      u32 m = mw[t + 256 * j];
      if (!(m == 0u || m == 1u || m == 0x3F800000u)) aw = 0;
      u32 lo = m & 0xFFFFu, hi = m >> 16;
      if (!((lo == 0u || lo == 1u || lo == 0x3F80u) && (hi == 0u || hi == 1u || hi == 0x3F80u))) ah = 0;
      if (m & ~0x01010101u) ab = 0;
    }
    if (!aw) atomicAnd(&s_aw, 0);
    if (!ah) atomicAnd(&s_ah, 0);
    if (!ab) atomicAnd(&s_ab, 0);
  }
  __syncthreads();
  int Fm = 0;
  if (s_aw) Fm = 0; else if (s_ab) Fm = 1; else if (s_ah) Fm = 2;

  if (Fm == 0){
    int lane = t & 63;
    int wid = blockIdx.x * 4 + (t >> 6);       // 8192 waves
    const u32* mw = (const u32*)maskv;
    size_t base = (size_t)wid * 2048;          // 32 iters x 64 words
    #pragma unroll 4
    for (int i = 0; i < 32; ++i){
      u32 v = mw[base + i * 64 + lane];
      unsigned long long bal = __ballot(v != 0u);
      if (lane < 2) Mb[(base + i * 64) / 32 + lane] = (u32)(bal >> (32 * lane));
    }
    return;
  }
  int oid = blockIdx.x * 256 + t;              // one packed word per thread
  u32 bits = 0;
  if (Fm == 1){
    const uint4* mp = (const uint4*)maskv + (size_t)oid * 2;
    #pragma unroll
    for (int k = 0; k < 2; ++k){
      uint4 v = mp[k];
      u32 w[4] = {v.x, v.y, v.z, v.w};
      #pragma unroll
      for (int q = 0; q < 4; ++q)
        #pragma unroll
        for (int bb = 0; bb < 4; ++bb)
          bits |= ((w[q] >> (8*bb)) & 255u ? 1u : 0u) << (k*16 + q*4 + bb);
    }
  } else {
    const uint4* mp = (const uint4*)maskv + (size_t)oid * 4;
    #pragma unroll
    for (int k = 0; k < 4; ++k){
      uint4 v = mp[k];
      u32 w[4] = {v.x, v.y, v.z, v.w};
      #pragma unroll
      for (int q = 0; q < 4; ++q){
        bits |= ((w[q] & 0xFFFFu) ? 1u : 0u) << (k*8 + q*2);
        bits |= ((w[q] >> 16)     ? 1u : 0u) << (k*8 + q*2 + 1);
      }
    }
  }
  Mb[oid] = bits;
}

// ---------------- fused prep (no mask branch) ----------------
// blocks [0,256): proj-B -> fragment-major f16 zF   (inlines WfB gather from WBw)
// blocks [256,768): e-tables (inlines vA/vB/cA/cB fold)
// blocks [768,832): WtO transpose of Ww
__global__ __launch_bounds__(256) void kprep(
    const float* __restrict__ hA, const float* __restrict__ hB,
    const float* __restrict__ WAw, const float* __restrict__ WAb,
    const float* __restrict__ aAw, const float* __restrict__ aAb,
    const float* __restrict__ WBw, const float* __restrict__ WBb,
    const float* __restrict__ aBw, const float* __restrict__ aBb,
    const float* __restrict__ Ww, float* __restrict__ WtO,
    uint4* __restrict__ zF,
    float* __restrict__ EAe, float* __restrict__ EA01e,
    u32* __restrict__ EBh, u32* __restrict__ GBh){
  __shared__ float smem[12416];       // 49,664 B; branch-local overlays
  int gid = blockIdx.x, t = threadIdx.x;

  if (gid < 256){
    // ---------------- proj-B ----------------
    float* h_l = smem;                // 32*132 = 4224
    float* W_l = smem + 4224;         // 64*128 = 8192
    float* T   = smem + 4224;         // 128*33 = 4224, overlays W_l after compute
    int R0 = gid * 32;

    for (int j = 0; j < 4; ++j){
      int idx4 = t + 256 * j;
      int r = idx4 >> 5, k0 = (idx4 & 31) * 4;
      *(float4*)&h_l[r * 132 + k0] = *(const float4*)&hB[(size_t)(R0 + r) * 128 + k0];
    }

    int cg = t & 15, rg = t >> 4;
    float acc[2][8];
    for (int i = 0; i < 2; ++i) for (int s = 0; s < 8; ++s) acc[i][s] = 0.f;

    for (int kc = 0; kc < 2; ++kc){
      __syncthreads();
      for (int j = 0; j < 8; ++j){
        int idx4 = t + 256 * j;
        int k = idx4 >> 5, c0 = (idx4 & 31) * 4;
        // WfB[(kc*64+k)*128 + c] == WBw[(c>>4)*2048 + (kc*64+k)*16 + (c&15)], contiguous x4
        *(float4*)&W_l[k * 128 + c0] =
          *(const float4*)&WBw[(size_t)(c0 >> 4) * 2048 + (kc * 64 + k) * 16 + (c0 & 15)];
      }
      __syncthreads();
      for (int k = 0; k < 64; ++k){
        int kk = kc * 64 + k;
        float4 w0 = *(const float4*)&W_l[k * 128 + cg * 8];
        float4 w1 = *(const float4*)&W_l[k * 128 + cg * 8 + 4];
        float wv[8] = {w0.x, w0.y, w0.z, w0.w, w1.x, w1.y, w1.z, w1.w};
        #pragma unroll
        for (int i = 0; i < 2; ++i){
          float hv = h_l[(rg * 2 + i) * 132 + kk];
          #pragma unroll
          for (int s = 0; s < 8; ++s) acc[i][s] = fmaf(hv, wv[s], acc[i][s]);
        }
      }
    }
    __syncthreads();                  // W_l reads done before T overlay
    for (int i = 0; i < 2; ++i)
      #pragma unroll
      for (int s = 0; s < 8; ++s)
        T[(cg * 8 + s) * 33 + rg * 2 + i] = acc[i][s] + WBb[cg * 8 + s];
    __syncthreads();

    int b = R0 >> 11;
    int mblk = (R0 & 2047) >> 5;
    for (int it = t; it < 512; it += 256){
      int h = it >> 6, lane = it & 63;
      int d = lane & 15, mq = (lane >> 4) * 8;
      const float* Tp = &T[(h * 16 + d) * 33 + mq];
      u32 wv2[4];
      #pragma unroll
      for (int p = 0; p < 4; ++p){
        union { f16x2 h2; u32 u; } c;
        c.h2 = (f16x2){(_Float16)Tp[p * 2], (_Float16)Tp[p * 2 + 1]};
        wv2[p] = c.u;
      }
      zF[((size_t)((b * 8 + h) * 64) + mblk) * 64 + lane] = make_uint4(wv2[0], wv2[1], wv2[2], wv2[3]);
    }
  } else if (gid < 768){
    // ---------------- e-tables (fold inlined) ----------------
    float* h_l = smem;                // 32*132
    float* v_l = smem + 4224;         // 8*132
    float* c_l = smem + 5280;         // 8
    float* a_l = smem + 5288;         // 128
    int ge = gid - 256;
    int X = ge >> 8;
    int r0 = (ge & 255) * 32;
    const float* hp  = X ? hB  : hA;
    const float* Wp  = X ? WBw : WAw;
    const float* Wbp = X ? WBb : WAb;
    const float* awp = X ? aBw : aAw;
    const float* abp = X ? aBb : aAb;

    for (int j = 0; j < 4; ++j){
      int idx4 = t + 256 * j;
      int r = idx4 >> 5, k0 = (idx4 & 31) * 4;
      *(float4*)&h_l[r * 132 + k0] = *(const float4*)&hp[(size_t)(r0 + r) * 128 + k0];
    }
    if (t < 128) a_l[t] = awp[t];
    __syncthreads();
    #pragma unroll
    for (int p = 0; p < 4; ++p){
      int idx = t + 256 * p;
      int h = idx >> 7, i = idx & 127;
      const float* wrow = Wp + (size_t)h * 2048 + i * 16;
      float s = 0.f;
      #pragma unroll
      for (int d = 0; d < 16; ++d) s = fmaf(wrow[d], a_l[h * 16 + d], s);
      v_l[h * 132 + i] = s;
    }
    if (t < 8){
      float s = abp[t];
      #pragma unroll
      for (int d = 0; d < 16; ++d) s = fmaf(Wbp[t * 16 + d], a_l[t * 16 + d], s);
      c_l[t] = s;
    }
    __syncthreads();

    int r = t >> 3, h = t & 7;
    float acc = c_l[h];
    #pragma unroll
    for (int k0 = 0; k0 < 128; k0 += 4){
      float4 hv = *(const float4*)&h_l[r * 132 + k0];
      float4 vv = *(const float4*)&v_l[h * 132 + k0];
      acc = fmaf(hv.x, vv.x, acc); acc = fmaf(hv.y, vv.y, acc);
      acc = fmaf(hv.z, vv.z, acc); acc = fmaf(hv.w, vv.w, acc);
    }
    int row = r0 + r;
    int b = row >> 11, n = row & 2047;
    float e0 = __expf(acc), e1 = __expf(0.01f * acc);
    if (X){
      float p0 = __shfl_xor(e0, 8, 64);
      float p1 = __shfl_xor(e1, 8, 64);
      if ((((t & 63) >> 3) & 1) == 0){
        union { f16x2 h2; u32 u; } c0, c1;
        c0.h2 = (f16x2){(_Float16)e0, (_Float16)p0};
        c1.h2 = (f16x2){(_Float16)e1, (_Float16)p1};
        u32 di = (u32)((b * 8 + h) * 1024 + (n >> 1));
        EBh[di] = c0.u;
        GBh[di] = c1.u;
      }
    } else {
      size_t idx = (size_t)(b * 8 + h) * 2048 + n;
      EAe[idx] = e0; EA01e[idx] = e1;
    }
  } else {
    // ---------------- WtO transpose ----------------
    int j = gid - 768;
    int idx = j * 256 + t;
    int c = idx >> 7, o = idx & 127;
    WtO[idx] = Ww[o * 128 + c];
  }
}

// ---------------- attention: f16 MFMA flash, LDS-staged EB/GB + mask, m-split x4 ----------------
__global__ __launch_bounds__(256) void kattn(const uint4* __restrict__ zF,
                                             const float* __restrict__ EAe, const float* __restrict__ EA01e,
                                             const u32* __restrict__ EBh, const u32* __restrict__ GBh,
                                             const u32* __restrict__ Mb,
                                             float* __restrict__ cat){
  __shared__ u32 EB_l[1024];         // full head: 2048 m as 1024 f16-pairs
  __shared__ u32 GB_l[1024];
  __shared__ u32 Mb_l[32 * 65];      // 32 n-rows x 64 m-words, stride-65 pad (conflict-free)
  __shared__ float red[3][32][17];   // [source wave-1][local row][16 cols + L]
  int t = threadIdx.x;
  int w = t >> 6, lane = t & 63;     // w = m-quarter
  int gid = blockIdx.x;              // 2048
  int h  = gid & 7;
  int nt = (gid >> 3) & 63;
  int b  = gid >> 9;
  int n0 = nt * 32;
  int nl = lane & 15, q = lane >> 4, qs = q * 8;

  // stage EB/GB (4KB+4KB) and the 8KB mask tile, all coalesced
  {
    const uint4* src0 = (const uint4*)(EBh + (size_t)(b * 8 + h) * 1024);
    const uint4* src1 = (const uint4*)(GBh + (size_t)(b * 8 + h) * 1024);
    ((uint4*)EB_l)[t] = src0[t];
    ((uint4*)GB_l)[t] = src1[t];
    const uint4* ms = (const uint4*)(Mb + ((size_t)b * 2048 + n0) * 64);
    uint4 m0v = ms[t * 2], m1v = ms[t * 2 + 1];
    int rr = t >> 3, cc = (t & 7) * 8;
    u32* dst = Mb_l + rr * 65 + cc;  // write banks 2-way max (free)
    dst[0] = m0v.x; dst[1] = m0v.y; dst[2] = m0v.z; dst[3] = m0v.w;
    dst[4] = m1v.x; dst[5] = m1v.y; dst[6] = m1v.z; dst[7] = m1v.w;
  }

  size_t ebase = (size_t)(b * 8 + h) * 2048;
  _Float16 ea0h  = (_Float16)EAe  [ebase + n0 + nl];
  _Float16 ea0sh = (_Float16)EA01e[ebase + n0 + nl];
  _Float16 ea1h  = (_Float16)EAe  [ebase + n0 + 16 + nl];
  _Float16 ea1sh = (_Float16)EA01e[ebase + n0 + 16 + nl];
  f16x2 ea0_2  = (f16x2){ea0h,  ea0h};
  f16x2 ea0s_2 = (f16x2){ea0sh, ea0sh};
  f16x2 ea1_2  = (f16x2){ea1h,  ea1h};
  f16x2 ea1s_2 = (f16x2){ea1sh, ea1sh};

  const u32* EBq = EB_l + w * 256;    // this wave's quarter (LDS)
  const u32* GBq = GB_l + w * 256;
  const u32* Mrow0 = Mb_l + nl * 65 + w * 16;        // row n0+nl
  const u32* Mrow1 = Mb_l + (nl + 16) * 65 + w * 16; // row n0+16+nl
  const uint4* zFp = zF + ((size_t)(b * 8 + h) * 64 + w * 16) * 64 + lane;  // coalesced

  f32x4 acc0 = {0.f,0.f,0.f,0.f}, acc1 = {0.f,0.f,0.f,0.f};
  f32x4 lcc0 = {0.f,0.f,0.f,0.f}, lcc1 = {0.f,0.f,0.f,0.f};
  union { u32 u[4]; f16x8 v; } onesu;
  onesu.u[0] = 0x3C003C00u; onesu.u[1] = 0x3C003C00u;
  onesu.u[2] = 0x3C003C00u; onesu.u[3] = 0x3C003C00u;
  const f16x8 ones = onesu.v;

  __syncthreads();                    // staging complete

  uint4 Azu, Bzu;
  #define LOADA(sp) do{ Azu = zFp[(size_t)(sp) * 64]; }while(0)
  #define LOADB(sp) do{ Bzu = zFp[(size_t)(sp) * 64]; }while(0)
  #define COMP(sp,ZU_) do{ \
    uint4 EB_ = *(const uint4*)(EBq + (sp) * 16 + q * 4); \
    uint4 GB_ = *(const uint4*)(GBq + (sp) * 16 + q * 4); \
    u32 mb0 = Mrow0[sp] >> qs; \
    u32 mb1 = Mrow1[sp] >> qs; \
    u32 ebu[4] = {EB_.x, EB_.y, EB_.z, EB_.w}; \
    u32 gbu[4] = {GB_.x, GB_.y, GB_.z, GB_.w}; \
    union { u32 u[4]; f16x8 v; } a0, a1; \
    _Pragma("unroll") \
    for (int p = 0; p < 4; ++p){ \
      int j0 = 2*p, j1 = 2*p + 1; \
      u32 k00 = SEXTBIT(mb0, j0); \
      u32 k01 = SEXTBIT(mb0, j1); \
      u32 k10 = SEXTBIT(mb1, j0); \
      u32 k11 = SEXTBIT(mb1, j1); \
      u32 kc0 = __builtin_amdgcn_perm(k01, k00, 0x05040100u); \
      u32 kc1 = __builtin_amdgcn_perm(k11, k10, 0x05040100u); \
      union { u32 u; f16x2 h2; } eb, gb, r0u, r1u; \
      eb.u = ebu[p]; gb.u = gbu[p]; \
      r0u.h2 = __builtin_elementwise_max(ea0_2 * eb.h2, ea0s_2 * gb.h2); \
      r1u.h2 = __builtin_elementwise_max(ea1_2 * eb.h2, ea1s_2 * gb.h2); \
      a0.u[p] = r0u.u & kc0; \
      a1.u[p] = r1u.u & kc1; \
    } \
    union { uint4 u; f16x8 v; } zu; zu.u = ZU_; \
    acc0 = __builtin_amdgcn_mfma_f32_16x16x32_f16(a0.v, zu.v, acc0, 0, 0, 0); \
    lcc0 = __builtin_amdgcn_mfma_f32_16x16x32_f16(a0.v, ones, lcc0, 0, 0, 0); \
    acc1 = __builtin_amdgcn_mfma_f32_16x16x32_f16(a1.v, zu.v, acc1, 0, 0, 0); \
    lcc1 = __builtin_amdgcn_mfma_f32_16x16x32_f16(a1.v, ones, lcc1, 0, 0, 0); }while(0)

  LOADA(0);
  LOADB(1);
  #pragma unroll 4
  for (int s = 0; s < 16; s += 2){
    COMP(s, Azu);
    LOADA(s + 2);                        // <=2-step overrun stays inside ws
    COMP(s + 1, Bzu);
    LOADB(s + 3);
  }
  #undef LOADA
  #undef LOADB
  #undef COMP

  if (w > 0){
    #pragma unroll
    for (int r = 0; r < 4; ++r){
      int row = q * 4 + r;
      red[w - 1][row][nl]      = acc0[r];
      red[w - 1][row + 16][nl] = acc1[r];
    }
    if (nl == 0){
      #pragma unroll
      for (int r = 0; r < 4; ++r){
        red[w - 1][q * 4 + r][16]      = lcc0[r];
        red[w - 1][q * 4 + r + 16][16] = lcc1[r];
      }
    }
  }
  __syncthreads();
  if (w == 0){
    #pragma unroll
    for (int r = 0; r < 4; ++r){
      int row = q * 4 + r;
      float a0 = acc0[r] + red[0][row][nl]      + red[1][row][nl]      + red[2][row][nl];
      float a1 = acc1[r] + red[0][row + 16][nl] + red[1][row + 16][nl] + red[2][row + 16][nl];
      float L0 = lcc0[r] + red[0][row][16]      + red[1][row][16]      + red[2][row][16];
      float L1 = lcc1[r] + red[0][row + 16][16] + red[1][row + 16][16] + red[2][row + 16][16];
      float r0 = (L0 > 0.f) ? 1.f / L0 : 0.f;
      float r1 = (L1 > 0.f) ? 1.f / L1 : 0.f;
      cat[((size_t)(b * 2048) + n0 + row)      * 128 + h * 16 + nl] = a0 * r0;
      cat[((size_t)(b * 2048) + n0 + 16 + row) * 128 + h * 16 + nl] = a1 * r1;
    }
  }
}

// ---------------- output GEMM: out = cat @ WtO + Wb ----------------
__global__ __launch_bounds__(256) void kout(const float* __restrict__ cat,
                                            const float* __restrict__ WtO, const float* __restrict__ Wb,
                                            float* __restrict__ out){
  __shared__ float cat_l[32 * 132];
  __shared__ float Wt_l[64 * 128];
  int R0 = blockIdx.x * 32;
  int t = threadIdx.x;

  for (int jj = 0; jj < 4; ++jj){
    int idx4 = t + 256 * jj;
    int r = idx4 >> 5, c0 = (idx4 & 31) * 4;
    *(float4*)&cat_l[r * 132 + c0] = *(const float4*)&cat[((size_t)R0 + r) * 128 + c0];
  }

  int og = t & 15, rg = t >> 4;
  float acc[2][8];
  for (int i = 0; i < 2; ++i) for (int s = 0; s < 8; ++s) acc[i][s] = 0.f;

  for (int kc = 0; kc < 2; ++kc){
    __syncthreads();
    for (int j = 0; j < 8; ++j){
      int idx4 = t + 256 * j;
      int k = idx4 >> 5, o0 = (idx4 & 31) * 4;
      *(float4*)&Wt_l[k * 128 + o0] = *(const float4*)&WtO[(kc * 64 + k) * 128 + o0];
    }
    __syncthreads();
    for (int k = 0; k < 64; ++k){
      int kk = kc * 64 + k;
      float4 w0 = *(const float4*)&Wt_l[k * 128 + og * 8];
      float4 w1 = *(const float4*)&Wt_l[k * 128 + og * 8 + 4];
      float wv[8] = {w0.x, w0.y, w0.z, w0.w, w1.x, w1.y, w1.z, w1.w};
      #pragma unroll
      for (int i = 0; i < 2; ++i){
        float cv = cat_l[(rg * 2 + i) * 132 + kk];
        #pragma unroll
        for (int s = 0; s < 8; ++s) acc[i][s] = fmaf(cv, wv[s], acc[i][s]);
      }
    }
  }

  for (int i = 0; i < 2; ++i){
    int r = rg * 2 + i;
    float* op = out + (size_t)(R0 + r) * 128 + og * 8;
    *(float4*)(op)     = make_float4(acc[i][0]+Wb[og*8+0], acc[i][1]+Wb[og*8+1], acc[i][2]+Wb[og*8+2], acc[i][3]+Wb[og*8+3]);
    *(float4*)(op + 4) = make_float4(acc[i][4]+Wb[og*8+4], acc[i][5]+Wb[og*8+5], acc[i][6]+Wb[og*8+6], acc[i][7]+Wb[og*8+7]);
  }
}

extern "C" void kernel_launch(void* const* d_in, const int* in_sizes, int n_in,
                              void* d_out, int out_size, void* d_ws, size_t ws_size,
                              hipStream_t stream) {
  const float* hA  = (const float*)d_in[0];
  const float* hB  = (const float*)d_in[1];
  const void* maskv= d_in[2];
  const float* WAw = (const float*)d_in[3];
  const float* WAb = (const float*)d_in[4];
  const float* WBw = (const float*)d_in[5];
  const float* WBb = (const float*)d_in[6];
  const float* aAw = (const float*)d_in[7];
  const float* aAb = (const float*)d_in[8];
  const float* aBw = (const float*)d_in[9];
  const float* aBb = (const float*)d_in[10];
  const float* Ww  = (const float*)d_in[11];
  const float* Wb  = (const float*)d_in[12];

  float* ws   = (float*)d_ws;
  uint4* zF   = (uint4*)ws;           // 131,072 uint4 = 524,288 float slots
  float* EAe  = ws + 524288;          // 65,536
  float* EA01e= ws + 589824;          // 65,536
  u32*  EBh   = (u32*)(ws + 655360);  // 32,768 dwords used (slot 65,536)
  u32*  GBh   = (u32*)(ws + 720896);  // 32,768 dwords used (slot 65,536)
  // ws + 786432: 16,384 (unused)
  float* WtO  = ws + 802816;          // 16,384
  u32*  Mb    = (u32*)(ws + 821272);  // 524,288
  float* cat  = ws + 1345560;         // 1,048,576 -> total 2,394,136 floats

  if (ws_size < 2394136ull * 4ull){
    kzero<<<4096, 256, 0, stream>>>((float*)d_out);
    return;
  }

  kmask<<<2048, 256, 0, stream>>>(maskv, Mb);
  kprep<<< 832, 256, 0, stream>>>(hA, hB,
                                  WAw, WAb, aAw, aAb,
                                  WBw, WBb, aBw, aBb,
                                  Ww, WtO, zF, EAe, EA01e, EBh, GBh);
  kattn<<<2048, 256, 0, stream>>>(zF, EAe, EA01e, EBh, GBh, Mb, cat);
  kout <<< 256, 256, 0, stream>>>(cat, WtO, Wb, (float*)d_out);
}

// Round 3
// 163.019 us; speedup vs baseline: 1.1812x; 1.0790x over previous
//
#include <hip/hip_runtime.h>

typedef unsigned short u16;
typedef unsigned int u32;
typedef unsigned char u8;

typedef _Float16 f16x8 __attribute__((ext_vector_type(8)));   // 8 f16 (4 VGPRs)
typedef _Float16 f16x2 __attribute__((ext_vector_type(2)));   // packed pair
typedef __attribute__((ext_vector_type(4))) float f32x4;

// B=4, NA=NB=2048, IN=128, H=8, DH=16, C=128, OUT=128
// 4-launch pipeline:
//   kmask_*  (mask -> packed bits; encoding chosen HOST-SIDE via in_sizes)
//   kprep    (proj-B + e-tables(rho) + WtO transpose, fused)
//   kattn    (f16 MFMA flash; rho-trick removes per-row ea scaling; LDS overlay)
//   kout     (output GEMM)

#if __has_builtin(__builtin_amdgcn_sbfe)
#define SEXTBIT(m, j) ((u32)__builtin_amdgcn_sbfe((int)(m), (u32)(j), 1u))
#else
#define SEXTBIT(m, j) ((u32)(((int)((m) << (31 - (j)))) >> 31))
#endif

__global__ __launch_bounds__(256) void kzero(float* __restrict__ out){
  out[blockIdx.x * 256 + threadIdx.x] = 0.f;
}

// ---------------- mask -> packed bits, fp32 words (pipelined ballot) ----------------
__global__ __launch_bounds__(256) void kmask_f32(const u32* __restrict__ mw,
                                                 u32* __restrict__ Mb){
  int t = threadIdx.x;
  int lane = t & 63;
  int wid = blockIdx.x * 4 + (t >> 6);       // 8192 waves
  size_t base = (size_t)wid * 2048;          // 32 iters x 64 words
  for (int i = 0; i < 32; i += 4){
    u32 v0 = mw[base + (size_t)(i + 0) * 64 + lane];
    u32 v1 = mw[base + (size_t)(i + 1) * 64 + lane];
    u32 v2 = mw[base + (size_t)(i + 2) * 64 + lane];
    u32 v3 = mw[base + (size_t)(i + 3) * 64 + lane];
    unsigned long long b0 = __ballot(v0 != 0u);
    unsigned long long b1 = __ballot(v1 != 0u);
    unsigned long long b2 = __ballot(v2 != 0u);
    unsigned long long b3 = __ballot(v3 != 0u);
    if (lane == 0){
      size_t o = base / 32 + (size_t)i * 2;  // word index, even -> 8B aligned
      *(unsigned long long*)&Mb[o + 0] = b0;
      *(unsigned long long*)&Mb[o + 2] = b1;
      *(unsigned long long*)&Mb[o + 4] = b2;
      *(unsigned long long*)&Mb[o + 6] = b3;
    }
  }
}

// ---------------- mask -> packed bits, 1-byte bools ----------------
__global__ __launch_bounds__(256) void kmask_b8(const void* __restrict__ maskv,
                                                u32* __restrict__ Mb){
  int oid = blockIdx.x * 256 + threadIdx.x;   // one packed word per thread
  u32 bits = 0;
  const uint4* mp = (const uint4*)maskv + (size_t)oid * 2;
  uint4 va = mp[0], vb = mp[1];
  u32 w[8] = {va.x, va.y, va.z, va.w, vb.x, vb.y, vb.z, vb.w};
  #pragma unroll
  for (int q = 0; q < 8; ++q)
    #pragma unroll
    for (int bb = 0; bb < 4; ++bb)
      bits |= ((w[q] >> (8 * bb)) & 255u ? 1u : 0u) << (q * 4 + bb);
  Mb[oid] = bits;
}

// ---------------- mask -> packed bits, 2-byte elems ----------------
__global__ __launch_bounds__(256) void kmask_b16(const void* __restrict__ maskv,
                                                 u32* __restrict__ Mb){
  int oid = blockIdx.x * 256 + threadIdx.x;
  u32 bits = 0;
  const uint4* mp = (const uint4*)maskv + (size_t)oid * 4;
  #pragma unroll
  for (int k = 0; k < 4; ++k){
    uint4 v = mp[k];
    u32 w[4] = {v.x, v.y, v.z, v.w};
    #pragma unroll
    for (int q = 0; q < 4; ++q){
      bits |= ((w[q] & 0xFFFFu) ? 1u : 0u) << (k * 8 + q * 2);
      bits |= ((w[q] >> 16)     ? 1u : 0u) << (k * 8 + q * 2 + 1);
    }
  }
  Mb[oid] = bits;
}

// ---------------- fallback: self-detecting (sizes ambiguous) ----------------
__global__ __launch_bounds__(256) void kmask_det(const void* __restrict__ maskv,
                                                 u32* __restrict__ Mb){
  __shared__ int s_aw, s_ab, s_ah;
  int t = threadIdx.x;
  if (t == 0){ s_aw = 1; s_ab = 1; s_ah = 1; }
  __syncthreads();
  {
    const u32* mw = (const u32*)maskv;
    int aw = 1, ah = 1, ab = 1;
    #pragma unroll
    for (int j = 0; j < 4; ++j){
      u32 m = mw[t + 256 * j];
      if (!(m == 0u || m == 1u || m == 0x3F800000u)) aw = 0;
      u32 lo = m & 0xFFFFu, hi = m >> 16;
      if (!((lo == 0u || lo == 1u || lo == 0x3F80u) && (hi == 0u || hi == 1u || hi == 0x3F80u))) ah = 0;
      if (m & ~0x01010101u) ab = 0;
    }
    unsigned long long fa = __ballot(!aw);
    unsigned long long fh = __ballot(!ah);
    unsigned long long fb = __ballot(!ab);
    if ((t & 63) == 0){
      if (fa) atomicAnd(&s_aw, 0);
      if (fh) atomicAnd(&s_ah, 0);
      if (fb) atomicAnd(&s_ab, 0);
    }
  }
  __syncthreads();
  int Fm = 0;
  if (s_aw) Fm = 0; else if (s_ab) Fm = 1; else if (s_ah) Fm = 2;

  if (Fm == 0){
    int lane = t & 63;
    int wid = blockIdx.x * 4 + (t >> 6);
    const u32* mw = (const u32*)maskv;
    size_t base = (size_t)wid * 2048;
    for (int i = 0; i < 32; i += 4){
      u32 v0 = mw[base + (size_t)(i + 0) * 64 + lane];
      u32 v1 = mw[base + (size_t)(i + 1) * 64 + lane];
      u32 v2 = mw[base + (size_t)(i + 2) * 64 + lane];
      u32 v3 = mw[base + (size_t)(i + 3) * 64 + lane];
      unsigned long long b0 = __ballot(v0 != 0u);
      unsigned long long b1 = __ballot(v1 != 0u);
      unsigned long long b2 = __ballot(v2 != 0u);
      unsigned long long b3 = __ballot(v3 != 0u);
      if (lane == 0){
        size_t o = base / 32 + (size_t)i * 2;
        *(unsigned long long*)&Mb[o + 0] = b0;
        *(unsigned long long*)&Mb[o + 2] = b1;
        *(unsigned long long*)&Mb[o + 4] = b2;
        *(unsigned long long*)&Mb[o + 6] = b3;
      }
    }
    return;
  }
  int oid = blockIdx.x * 256 + t;
  u32 bits = 0;
  if (Fm == 1){
    const uint4* mp = (const uint4*)maskv + (size_t)oid * 2;
    #pragma unroll
    for (int k = 0; k < 2; ++k){
      uint4 v = mp[k];
      u32 w[4] = {v.x, v.y, v.z, v.w};
      #pragma unroll
      for (int q = 0; q < 4; ++q)
        #pragma unroll
        for (int bb = 0; bb < 4; ++bb)
          bits |= ((w[q] >> (8*bb)) & 255u ? 1u : 0u) << (k*16 + q*4 + bb);
    }
  } else {
    const uint4* mp = (const uint4*)maskv + (size_t)oid * 4;
    #pragma unroll
    for (int k = 0; k < 4; ++k){
      uint4 v = mp[k];
      u32 w[4] = {v.x, v.y, v.z, v.w};
      #pragma unroll
      for (int q = 0; q < 4; ++q){
        bits |= ((w[q] & 0xFFFFu) ? 1u : 0u) << (k*8 + q*2);
        bits |= ((w[q] >> 16)     ? 1u : 0u) << (k*8 + q*2 + 1);
      }
    }
  }
  Mb[oid] = bits;
}

// ---------------- fused prep ----------------
// blocks [0,256): proj-B -> fragment-major f16 zF
// blocks [256,768): e-tables; A-side writes rho = exp(-0.99*acc); B-side EBh/GBh
// blocks [768,832): WtO transpose of Ww
__global__ __launch_bounds__(256) void kprep(
    const float* __restrict__ hA, const float* __restrict__ hB,
    const float* __restrict__ WAw, const float* __restrict__ WAb,
    const float* __restrict__ aAw, const float* __restrict__ aAb,
    const float* __restrict__ WBw, const float* __restrict__ WBb,
    const float* __restrict__ aBw, const float* __restrict__ aBb,
    const float* __restrict__ Ww, float* __restrict__ WtO,
    uint4* __restrict__ zF,
    float* __restrict__ RA,
    u32* __restrict__ EBh, u32* __restrict__ GBh){
  __shared__ float smem[12416];       // 49,664 B; branch-local overlays
  int gid = blockIdx.x, t = threadIdx.x;

  if (gid < 256){
    // ---------------- proj-B ----------------
    float* h_l = smem;                // 32*132 = 4224
    float* W_l = smem + 4224;         // 64*128 = 8192
    float* T   = smem + 4224;         // 128*33 = 4224, overlays W_l after compute
    int R0 = gid * 32;

    for (int j = 0; j < 4; ++j){
      int idx4 = t + 256 * j;
      int r = idx4 >> 5, k0 = (idx4 & 31) * 4;
      *(float4*)&h_l[r * 132 + k0] = *(const float4*)&hB[(size_t)(R0 + r) * 128 + k0];
    }

    int cg = t & 15, rg = t >> 4;
    float acc[2][8];
    for (int i = 0; i < 2; ++i) for (int s = 0; s < 8; ++s) acc[i][s] = 0.f;

    for (int kc = 0; kc < 2; ++kc){
      __syncthreads();
      for (int j = 0; j < 8; ++j){
        int idx4 = t + 256 * j;
        int k = idx4 >> 5, c0 = (idx4 & 31) * 4;
        *(float4*)&W_l[k * 128 + c0] =
          *(const float4*)&WBw[(size_t)(c0 >> 4) * 2048 + (kc * 64 + k) * 16 + (c0 & 15)];
      }
      __syncthreads();
      for (int k = 0; k < 64; ++k){
        int kk = kc * 64 + k;
        float4 w0 = *(const float4*)&W_l[k * 128 + cg * 8];
        float4 w1 = *(const float4*)&W_l[k * 128 + cg * 8 + 4];
        float wv[8] = {w0.x, w0.y, w0.z, w0.w, w1.x, w1.y, w1.z, w1.w};
        #pragma unroll
        for (int i = 0; i < 2; ++i){
          float hv = h_l[(rg * 2 + i) * 132 + kk];
          #pragma unroll
          for (int s = 0; s < 8; ++s) acc[i][s] = fmaf(hv, wv[s], acc[i][s]);
        }
      }
    }
    __syncthreads();                  // W_l reads done before T overlay
    for (int i = 0; i < 2; ++i)
      #pragma unroll
      for (int s = 0; s < 8; ++s)
        T[(cg * 8 + s) * 33 + rg * 2 + i] = acc[i][s] + WBb[cg * 8 + s];
    __syncthreads();

    int b = R0 >> 11;
    int mblk = (R0 & 2047) >> 5;
    for (int it = t; it < 512; it += 256){
      int h = it >> 6, lane = it & 63;
      int d = lane & 15, mq = (lane >> 4) * 8;
      const float* Tp = &T[(h * 16 + d) * 33 + mq];
      u32 wv2[4];
      #pragma unroll
      for (int p = 0; p < 4; ++p){
        union { f16x2 h2; u32 u; } c;
        c.h2 = (f16x2){(_Float16)Tp[p * 2], (_Float16)Tp[p * 2 + 1]};
        wv2[p] = c.u;
      }
      zF[((size_t)((b * 8 + h) * 64) + mblk) * 64 + lane] = make_uint4(wv2[0], wv2[1], wv2[2], wv2[3]);
    }
  } else if (gid < 768){
    // ---------------- e-tables (fold inlined) ----------------
    float* h_l = smem;                // 32*132
    float* v_l = smem + 4224;         // 8*132
    float* c_l = smem + 5280;         // 8
    float* a_l = smem + 5288;         // 128
    int ge = gid - 256;
    int X = ge >> 8;
    int r0 = (ge & 255) * 32;
    const float* hp  = X ? hB  : hA;
    const float* Wp  = X ? WBw : WAw;
    const float* Wbp = X ? WBb : WAb;
    const float* awp = X ? aBw : aAw;
    const float* abp = X ? aBb : aAb;

    for (int j = 0; j < 4; ++j){
      int idx4 = t + 256 * j;
      int r = idx4 >> 5, k0 = (idx4 & 31) * 4;
      *(float4*)&h_l[r * 132 + k0] = *(const float4*)&hp[(size_t)(r0 + r) * 128 + k0];
    }
    if (t < 128) a_l[t] = awp[t];
    __syncthreads();
    #pragma unroll
    for (int p = 0; p < 4; ++p){
      int idx = t + 256 * p;
      int h = idx >> 7, i = idx & 127;
      const float* wrow = Wp + (size_t)h * 2048 + i * 16;
      float s = 0.f;
      #pragma unroll
      for (int d = 0; d < 16; ++d) s = fmaf(wrow[d], a_l[h * 16 + d], s);
      v_l[h * 132 + i] = s;
    }
    if (t < 8){
      float s = abp[t];
      #pragma unroll
      for (int d = 0; d < 16; ++d) s = fmaf(Wbp[t * 16 + d], a_l[t * 16 + d], s);
      c_l[t] = s;
    }
    __syncthreads();

    int r = t >> 3, h = t & 7;
    float acc = c_l[h];
    #pragma unroll
    for (int k0 = 0; k0 < 128; k0 += 4){
      float4 hv = *(const float4*)&h_l[r * 132 + k0];
      float4 vv = *(const float4*)&v_l[h * 132 + k0];
      acc = fmaf(hv.x, vv.x, acc); acc = fmaf(hv.y, vv.y, acc);
      acc = fmaf(hv.z, vv.z, acc); acc = fmaf(hv.w, vv.w, acc);
    }
    int row = r0 + r;
    int b = row >> 11, n = row & 2047;
    if (X){
      float e0 = __expf(acc), e1 = __expf(0.01f * acc);
      float p0 = __shfl_xor(e0, 8, 64);
      float p1 = __shfl_xor(e1, 8, 64);
      if ((((t & 63) >> 3) & 1) == 0){
        union { f16x2 h2; u32 u; } c0, c1;
        c0.h2 = (f16x2){(_Float16)e0, (_Float16)p0};
        c1.h2 = (f16x2){(_Float16)e1, (_Float16)p1};
        u32 di = (u32)((b * 8 + h) * 1024 + (n >> 1));
        EBh[di] = c0.u;
        GBh[di] = c1.u;
      }
    } else {
      // rho = exp(0.01a)/exp(a) = exp(-0.99a): per-row ea cancels in acc/L
      RA[(size_t)(b * 8 + h) * 2048 + n] = __expf(-0.99f * acc);
    }
  } else {
    // ---------------- WtO transpose ----------------
    int j = gid - 768;
    int idx = j * 256 + t;
    int c = idx >> 7, o = idx & 127;
    WtO[idx] = Ww[o * 128 + c];
  }
}

// ---------------- attention: f16 MFMA flash, rho-trick, LDS overlay ----------------
__global__ __launch_bounds__(256) void kattn(const uint4* __restrict__ zF,
                                             const float* __restrict__ RA,
                                             const u32* __restrict__ EBh, const u32* __restrict__ GBh,
                                             const u32* __restrict__ Mb,
                                             float* __restrict__ cat){
  __shared__ u32 EB_l[1024];         // full head: 2048 m as 1024 f16-pairs
  __shared__ u32 GB_l[1024];
  __shared__ u32 MR_l[32 * 65];      // mask tile (main loop) / red (epilogue) overlay
  u32* Mb_l = MR_l;
  float (*red)[32][17] = (float(*)[32][17])MR_l;  // 3*32*17*4 = 6528 B <= 8320 B
  int t = threadIdx.x;
  int w = t >> 6, lane = t & 63;     // w = m-quarter
  int gid = blockIdx.x;              // 2048
  int h  = gid & 7;
  int nt = (gid >> 3) & 63;
  int b  = gid >> 9;
  int n0 = nt * 32;
  int nl = lane & 15, q = lane >> 4, qs = q * 8;

  // stage EB/GB (4KB+4KB) and the 8KB mask tile, all coalesced
  {
    const uint4* src0 = (const uint4*)(EBh + (size_t)(b * 8 + h) * 1024);
    const uint4* src1 = (const uint4*)(GBh + (size_t)(b * 8 + h) * 1024);
    ((uint4*)EB_l)[t] = src0[t];
    ((uint4*)GB_l)[t] = src1[t];
    const uint4* ms = (const uint4*)(Mb + ((size_t)b * 2048 + n0) * 64);
    uint4 m0v = ms[t * 2], m1v = ms[t * 2 + 1];
    int rr = t >> 3, cc = (t & 7) * 8;
    u32* dst = Mb_l + rr * 65 + cc;  // write banks 2-way max (free)
    dst[0] = m0v.x; dst[1] = m0v.y; dst[2] = m0v.z; dst[3] = m0v.w;
    dst[4] = m1v.x; dst[5] = m1v.y; dst[6] = m1v.z; dst[7] = m1v.w;
  }

  size_t ebase = (size_t)(b * 8 + h) * 2048;
  float ra0 = RA[ebase + n0 + nl];
  float ra1 = RA[ebase + n0 + 16 + nl];
  f16x2 rho0_2 = (f16x2){(_Float16)ra0, (_Float16)ra0};
  f16x2 rho1_2 = (f16x2){(_Float16)ra1, (_Float16)ra1};

  const u32* EBq = EB_l + w * 256;    // this wave's quarter (LDS)
  const u32* GBq = GB_l + w * 256;
  const u32* Mrow0 = Mb_l + nl * 65 + w * 16;        // row n0+nl
  const u32* Mrow1 = Mb_l + (nl + 16) * 65 + w * 16; // row n0+16+nl
  const uint4* zFp = zF + ((size_t)(b * 8 + h) * 64 + w * 16) * 64 + lane;  // coalesced

  f32x4 acc0 = {0.f,0.f,0.f,0.f}, acc1 = {0.f,0.f,0.f,0.f};
  f32x4 lcc0 = {0.f,0.f,0.f,0.f}, lcc1 = {0.f,0.f,0.f,0.f};
  union { u32 u[4]; f16x8 v; } onesu;
  onesu.u[0] = 0x3C003C00u; onesu.u[1] = 0x3C003C00u;
  onesu.u[2] = 0x3C003C00u; onesu.u[3] = 0x3C003C00u;
  const f16x8 ones = onesu.v;

  __syncthreads();                    // staging complete

  uint4 Azu, Bzu;
  #define LOADA(sp) do{ Azu = zFp[(size_t)(sp) * 64]; }while(0)
  #define LOADB(sp) do{ Bzu = zFp[(size_t)(sp) * 64]; }while(0)
  #define COMP(sp,ZU_) do{ \
    uint4 EB_ = *(const uint4*)(EBq + (sp) * 16 + q * 4); \
    uint4 GB_ = *(const uint4*)(GBq + (sp) * 16 + q * 4); \
    u32 mb0 = Mrow0[sp] >> qs; \
    u32 mb1 = Mrow1[sp] >> qs; \
    u32 ebu[4] = {EB_.x, EB_.y, EB_.z, EB_.w}; \
    u32 gbu[4] = {GB_.x, GB_.y, GB_.z, GB_.w}; \
    union { u32 u[4]; f16x8 v; } a0, a1; \
    _Pragma("unroll") \
    for (int p = 0; p < 4; ++p){ \
      int j0 = 2*p, j1 = 2*p + 1; \
      u32 k00 = SEXTBIT(mb0, j0); \
      u32 k01 = SEXTBIT(mb0, j1); \
      u32 k10 = SEXTBIT(mb1, j0); \
      u32 k11 = SEXTBIT(mb1, j1); \
      u32 kc0 = __builtin_amdgcn_perm(k01, k00, 0x05040100u); \
      u32 kc1 = __builtin_amdgcn_perm(k11, k10, 0x05040100u); \
      union { u32 u; f16x2 h2; } eb, gb, r0u, r1u; \
      eb.u = ebu[p]; gb.u = gbu[p]; \
      r0u.h2 = __builtin_elementwise_max(eb.h2, rho0_2 * gb.h2); \
      r1u.h2 = __builtin_elementwise_max(eb.h2, rho1_2 * gb.h2); \
      a0.u[p] = r0u.u & kc0; \
      a1.u[p] = r1u.u & kc1; \
    } \
    union { uint4 u; f16x8 v; } zu; zu.u = ZU_; \
    acc0 = __builtin_amdgcn_mfma_f32_16x16x32_f16(a0.v, zu.v, acc0, 0, 0, 0); \
    lcc0 = __builtin_amdgcn_mfma_f32_16x16x32_f16(a0.v, ones, lcc0, 0, 0, 0); \
    acc1 = __builtin_amdgcn_mfma_f32_16x16x32_f16(a1.v, zu.v, acc1, 0, 0, 0); \
    lcc1 = __builtin_amdgcn_mfma_f32_16x16x32_f16(a1.v, ones, lcc1, 0, 0, 0); }while(0)

  LOADA(0);
  LOADB(1);
  #pragma unroll 4
  for (int s = 0; s < 16; s += 2){
    COMP(s, Azu);
    LOADA(s + 2);                        // <=2-step overrun stays inside ws
    COMP(s + 1, Bzu);
    LOADB(s + 3);
  }
  #undef LOADA
  #undef LOADB
  #undef COMP

  __syncthreads();                    // all waves done reading Mb_l before red overlay
  if (w > 0){
    #pragma unroll
    for (int r = 0; r < 4; ++r){
      int row = q * 4 + r;
      red[w - 1][row][nl]      = acc0[r];
      red[w - 1][row + 16][nl] = acc1[r];
    }
    if (nl == 0){
      #pragma unroll
      for (int r = 0; r < 4; ++r){
        red[w - 1][q * 4 + r][16]      = lcc0[r];
        red[w - 1][q * 4 + r + 16][16] = lcc1[r];
      }
    }
  }
  __syncthreads();
  if (w == 0){
    #pragma unroll
    for (int r = 0; r < 4; ++r){
      int row = q * 4 + r;
      float a0 = acc0[r] + red[0][row][nl]      + red[1][row][nl]      + red[2][row][nl];
      float a1 = acc1[r] + red[0][row + 16][nl] + red[1][row + 16][nl] + red[2][row + 16][nl];
      float L0 = lcc0[r] + red[0][row][16]      + red[1][row][16]      + red[2][row][16];
      float L1 = lcc1[r] + red[0][row + 16][16] + red[1][row + 16][16] + red[2][row + 16][16];
      float r0 = (L0 > 0.f) ? 1.f / L0 : 0.f;
      float r1 = (L1 > 0.f) ? 1.f / L1 : 0.f;
      cat[((size_t)(b * 2048) + n0 + row)      * 128 + h * 16 + nl] = a0 * r0;
      cat[((size_t)(b * 2048) + n0 + 16 + row) * 128 + h * 16 + nl] = a1 * r1;
    }
  }
}

// ---------------- output GEMM: out = cat @ WtO + Wb ----------------
__global__ __launch_bounds__(256) void kout(const float* __restrict__ cat,
                                            const float* __restrict__ WtO, const float* __restrict__ Wb,
                                            float* __restrict__ out){
  __shared__ float cat_l[32 * 132];
  __shared__ float Wt_l[64 * 128];
  int R0 = blockIdx.x * 32;
  int t = threadIdx.x;

  for (int jj = 0; jj < 4; ++jj){
    int idx4 = t + 256 * jj;
    int r = idx4 >> 5, c0 = (idx4 & 31) * 4;
    *(float4*)&cat_l[r * 132 + c0] = *(const float4*)&cat[((size_t)R0 + r) * 128 + c0];
  }

  int og = t & 15, rg = t >> 4;
  float acc[2][8];
  for (int i = 0; i < 2; ++i) for (int s = 0; s < 8; ++s) acc[i][s] = 0.f;

  for (int kc = 0; kc < 2; ++kc){
    __syncthreads();
    for (int j = 0; j < 8; ++j){
      int idx4 = t + 256 * j;
      int k = idx4 >> 5, o0 = (idx4 & 31) * 4;
      *(float4*)&Wt_l[k * 128 + o0] = *(const float4*)&WtO[(kc * 64 + k) * 128 + o0];
    }
    __syncthreads();
    for (int k = 0; k < 64; ++k){
      int kk = kc * 64 + k;
      float4 w0 = *(const float4*)&Wt_l[k * 128 + og * 8];
      float4 w1 = *(const float4*)&Wt_l[k * 128 + og * 8 + 4];
      float wv[8] = {w0.x, w0.y, w0.z, w0.w, w1.x, w1.y, w1.z, w1.w};
      #pragma unroll
      for (int i = 0; i < 2; ++i){
        float cv = cat_l[(rg * 2 + i) * 132 + kk];
        #pragma unroll
        for (int s = 0; s < 8; ++s) acc[i][s] = fmaf(cv, wv[s], acc[i][s]);
      }
    }
  }

  for (int i = 0; i < 2; ++i){
    int r = rg * 2 + i;
    float* op = out + (size_t)(R0 + r) * 128 + og * 8;
    *(float4*)(op)     = make_float4(acc[i][0]+Wb[og*8+0], acc[i][1]+Wb[og*8+1], acc[i][2]+Wb[og*8+2], acc[i][3]+Wb[og*8+3]);
    *(float4*)(op + 4) = make_float4(acc[i][4]+Wb[og*8+4], acc[i][5]+Wb[og*8+5], acc[i][6]+Wb[og*8+6], acc[i][7]+Wb[og*8+7]);
  }
}

extern "C" void kernel_launch(void* const* d_in, const int* in_sizes, int n_in,
                              void* d_out, int out_size, void* d_ws, size_t ws_size,
                              hipStream_t stream) {
  const float* hA  = (const float*)d_in[0];
  const float* hB  = (const float*)d_in[1];
  const void* maskv= d_in[2];
  const float* WAw = (const float*)d_in[3];
  const float* WAb = (const float*)d_in[4];
  const float* WBw = (const float*)d_in[5];
  const float* WBb = (const float*)d_in[6];
  const float* aAw = (const float*)d_in[7];
  const float* aAb = (const float*)d_in[8];
  const float* aBw = (const float*)d_in[9];
  const float* aBb = (const float*)d_in[10];
  const float* Ww  = (const float*)d_in[11];
  const float* Wb  = (const float*)d_in[12];

  float* ws   = (float*)d_ws;
  uint4* zF   = (uint4*)ws;           // 131,072 uint4 = 524,288 float slots
  float* RA   = ws + 524288;          // 65,536  (rho table; former EAe slot)
  // ws + 589824: 65,536 (unused, former EA01e)
  u32*  EBh   = (u32*)(ws + 655360);  // 32,768 dwords used (slot 65,536)
  u32*  GBh   = (u32*)(ws + 720896);  // 32,768 dwords used (slot 65,536)
  float* WtO  = ws + 802816;          // 16,384
  u32*  Mb    = (u32*)(ws + 821272);  // 524,288
  float* cat  = ws + 1345560;         // 1,048,576 -> total 2,394,136 floats

  if (ws_size < 2394136ull * 4ull){
    kzero<<<4096, 256, 0, stream>>>((float*)d_out);
    return;
  }

  // mask encoding from in_sizes: only trust it if sizes are clearly BYTES
  // (h_A = 4*2048*128 fp32 = 4,194,304 B; elem-count would read 1,048,576)
  const long long ME = 4ll * 2048 * 2048;
  long long hsz = in_sizes[0];
  long long msz = in_sizes[2];
  bool bytes_known = (hsz == 4ll * 2048 * 128 * 4);
  if (bytes_known && msz == ME)
    kmask_b8 <<<2048, 256, 0, stream>>>(maskv, Mb);
  else if (bytes_known && msz == 2 * ME)
    kmask_b16<<<2048, 256, 0, stream>>>(maskv, Mb);
  else if (bytes_known && msz == 4 * ME)
    kmask_f32<<<2048, 256, 0, stream>>>((const u32*)maskv, Mb);
  else
    kmask_det<<<2048, 256, 0, stream>>>(maskv, Mb);

  kprep<<< 832, 256, 0, stream>>>(hA, hB,
                                  WAw, WAb, aAw, aAb,
                                  WBw, WBb, aBw, aBb,
                                  Ww, WtO, zF, RA, EBh, GBh);
  kattn<<<2048, 256, 0, stream>>>(zF, RA, EBh, GBh, Mb, cat);
  kout <<< 256, 256, 0, stream>>>(cat, WtO, Wb, (float*)d_out);
}